// Round 7
// baseline (268.542 us; speedup 1.0000x reference)
//
#include <hip/hip_runtime.h>
#include <math.h>

constexpr int D = 128;       // in_channels
constexpr int B = 512;       // batch_size (graphs)
constexpr int STEPS = 3;
constexpr int NW_IH = 3 * D * 2 * D;   // 98304 elems, Wih [3D][2D]
constexpr int NW_HH = 3 * D * D;       // 49152 elems, Whh [3D][D]

__device__ __forceinline__ float sigmoidf_(float x) { return 1.f / (1.f + __expf(-x)); }
// bf16 pair unpack from a uint: low halfword / high halfword -> float (exact)
__device__ __forceinline__ float bflo(unsigned int u) { return __uint_as_float(u << 16); }
__device__ __forceinline__ float bfhi(unsigned int u) { return __uint_as_float(u & 0xffff0000u); }
__device__ __forceinline__ unsigned short f2bf_rn(float f) {
    unsigned int u = __float_as_uint(f);
    u += 0x7fffu + ((u >> 16) & 1u);    // round-to-nearest-even
    return (unsigned short)(u >> 16);
}

// ---------------------------------------------------------------------------
// K0 (prep): weights fp32 -> bf16 row-major (R4 layout — proven fastest),
// plus segment bounds via binary search on sorted batch[].
// ---------------------------------------------------------------------------
__global__ __launch_bounds__(256) void k_prep(const float* __restrict__ Wih,
        const float* __restrict__ Whh, const int* __restrict__ batch, int n,
        unsigned short* __restrict__ wih_bf, unsigned short* __restrict__ whh_bf,
        int* __restrict__ seg) {
    int i = blockIdx.x * blockDim.x + threadIdx.x;
    if (i < NW_IH) wih_bf[i] = f2bf_rn(Wih[i]);
    else if (i < NW_IH + NW_HH) whh_bf[i - NW_IH] = f2bf_rn(Whh[i - NW_IH]);
    if (i <= B) {
        int lo = 0, hi = n;
        while (lo < hi) { int mid = (lo + hi) >> 1; if (batch[mid] < i) lo = mid + 1; else hi = mid; }
        seg[i] = lo;
    }
}

// ---------------------------------------------------------------------------
// K1 (k_cg): combine previous step's attention partials into r, then GRU.
// One block per graph, 384 threads (one gate row each).
//   C:  r[t] = (sum_j w_j * Pacc[g][j][t]) / (sum_j w_j * Pl[g][j] + eps),
//       w_j = exp(Pm[g][j] - max_j Pm), guarded for empty segments.
//   GRU: q_star = [h_prev | r]; gate rows with bf16 weights, 4 fma chains.
// first=1: q_star = 0, h = 0 (step 0) — also initializes g_h (no memset).
// ---------------------------------------------------------------------------
__global__ __launch_bounds__(384) void k_cg(
        const unsigned short* __restrict__ wih_bf,
        const unsigned short* __restrict__ whh_bf,
        const float* __restrict__ bih, const float* __restrict__ bhh,
        float* __restrict__ g_h,
        const float* __restrict__ Pm, const float* __restrict__ Pl,
        const float* __restrict__ Pacc, int first) {
    __shared__ float s_q[2 * D];
    __shared__ float s_h[D];
    __shared__ float s_gi[3 * D], s_gh[3 * D];
    const int g = blockIdx.x;
    const int t = threadIdx.x;

    if (t < D) {
        float hp = first ? 0.f : g_h[(size_t)g * D + t];
        s_h[t] = hp;
        s_q[t] = hp;                      // q part of q_star = previous h
        float r = 0.f;
        if (!first) {
            float m0 = Pm[g * 4 + 0], m1 = Pm[g * 4 + 1];
            float m2 = Pm[g * 4 + 2], m3 = Pm[g * 4 + 3];
            float M = fmaxf(fmaxf(m0, m1), fmaxf(m2, m3));
            float w0 = (m0 == -INFINITY) ? 0.f : __expf(m0 - M);
            float w1 = (m1 == -INFINITY) ? 0.f : __expf(m1 - M);
            float w2 = (m2 == -INFINITY) ? 0.f : __expf(m2 - M);
            float w3 = (m3 == -INFINITY) ? 0.f : __expf(m3 - M);
            float l = w0 * Pl[g * 4 + 0] + w1 * Pl[g * 4 + 1]
                    + w2 * Pl[g * 4 + 2] + w3 * Pl[g * 4 + 3];
            float inv = 1.f / (l + 1e-16f);
            r = (w0 * Pacc[(size_t)(g * 4 + 0) * D + t]
               + w1 * Pacc[(size_t)(g * 4 + 1) * D + t]
               + w2 * Pacc[(size_t)(g * 4 + 2) * D + t]
               + w3 * Pacc[(size_t)(g * 4 + 3) * D + t]) * inv;
        }
        s_q[D + t] = r;                   // r part of q_star
    }
    __syncthreads();

    // ---- gate row t (4 parallel fma chains, bf16x8 per uint4) ----
    {
        float a0 = bih[t], a1 = 0.f, a2 = 0.f, a3 = 0.f;
        const uint4* wr = (const uint4*)(wih_bf + (size_t)t * (2 * D));
#pragma unroll 4
        for (int c = 0; c < (2 * D) / 8; ++c) {     // 32 iters
            uint4 w = wr[c];
            const float* q = &s_q[c * 8];
            a0 = fmaf(bflo(w.x), q[0], a0); a0 = fmaf(bfhi(w.x), q[1], a0);
            a1 = fmaf(bflo(w.y), q[2], a1); a1 = fmaf(bfhi(w.y), q[3], a1);
            a2 = fmaf(bflo(w.z), q[4], a2); a2 = fmaf(bfhi(w.z), q[5], a2);
            a3 = fmaf(bflo(w.w), q[6], a3); a3 = fmaf(bfhi(w.w), q[7], a3);
        }
        s_gi[t] = (a0 + a1) + (a2 + a3);
        float b0 = bhh[t], b1 = 0.f, b2 = 0.f, b3 = 0.f;
        const uint4* vr = (const uint4*)(whh_bf + (size_t)t * D);
#pragma unroll 4
        for (int c = 0; c < D / 8; ++c) {           // 16 iters
            uint4 w = vr[c];
            const float* hh = &s_h[c * 8];
            b0 = fmaf(bflo(w.x), hh[0], b0); b0 = fmaf(bfhi(w.x), hh[1], b0);
            b1 = fmaf(bflo(w.y), hh[2], b1); b1 = fmaf(bfhi(w.y), hh[3], b1);
            b2 = fmaf(bflo(w.z), hh[4], b2); b2 = fmaf(bfhi(w.z), hh[5], b2);
            b3 = fmaf(bflo(w.w), hh[6], b3); b3 = fmaf(bfhi(w.w), hh[7], b3);
        }
        s_gh[t] = (b0 + b1) + (b2 + b3);
    }
    __syncthreads();

    // ---- epilogue: h_new -> g_h ----
    if (t < D) {
        float r  = sigmoidf_(s_gi[t] + s_gh[t]);
        float z  = sigmoidf_(s_gi[D + t] + s_gh[D + t]);
        float nn = tanhf(s_gi[2 * D + t] + r * s_gh[2 * D + t]);
        float hn = (1.f - z) * nn + z * s_h[t];
        g_h[(size_t)g * D + t] = hn;
    }
}

// ---------------------------------------------------------------------------
// K2 (k_attn_p): flash-attention PARTIALS. 2048 blocks x 256 threads
// (8 blocks/CU -> barrier/combine stalls of one block hidden by 7 others).
// Block 4g+j handles quarter j of graph g's node range; 8 half-waves stream
// nodes (float4/lane dot + 5-step xor reduce, online m/l/acc); writes
// (Pm, Pl, Pacc[128]) rescaled to the block max.
// ---------------------------------------------------------------------------
__global__ __launch_bounds__(256, 8) void k_attn_p(const float* __restrict__ x,
        const float* __restrict__ g_h, const int* __restrict__ seg,
        float* __restrict__ Pm, float* __restrict__ Pl,
        float* __restrict__ Pacc) {
    const int bid = blockIdx.x;
    const int g = bid >> 2, j = bid & 3;
    const int s = seg[g], e = seg[g + 1];
    const int len = e - s;
    const int qs = s + (len * j) / 4;
    const int qe = s + (len * (j + 1)) / 4;

    const int tid = threadIdx.x;
    const int lane32 = tid & 31;
    const int hw = tid >> 5;              // half-wave id 0..7

    const float4 qf = ((const float4*)(g_h + (size_t)g * D))[lane32];

    float m_run = -INFINITY, l_run = 0.f;
    float4 acc = {0.f, 0.f, 0.f, 0.f};
    for (int node = qs + hw; node < qe; node += 8) {
        float4 xv = ((const float4*)(x + (size_t)node * D))[lane32];
        float p = fmaf(xv.x, qf.x, fmaf(xv.y, qf.y, fmaf(xv.z, qf.z, xv.w * qf.w)));
        p += __shfl_xor(p, 16, 64);
        p += __shfl_xor(p, 8, 64);
        p += __shfl_xor(p, 4, 64);
        p += __shfl_xor(p, 2, 64);
        p += __shfl_xor(p, 1, 64);
        float nm = fmaxf(m_run, p);
        float scale = __expf(m_run - nm);   // 0 on first iter
        float a = __expf(p - nm);
        l_run = fmaf(l_run, scale, a);
        acc.x = fmaf(acc.x, scale, a * xv.x);
        acc.y = fmaf(acc.y, scale, a * xv.y);
        acc.z = fmaf(acc.z, scale, a * xv.z);
        acc.w = fmaf(acc.w, scale, a * xv.w);
        m_run = nm;
    }

    __shared__ float sm[8], sl[8];
    __shared__ float s_M;
    if (lane32 == 0) { sm[hw] = m_run; sl[hw] = l_run; }
    __syncthreads();
    if (tid == 0) {
        float M = -INFINITY;
#pragma unroll
        for (int i = 0; i < 8; ++i) M = fmaxf(M, sm[i]);
        float L = 0.f;
#pragma unroll
        for (int i = 0; i < 8; ++i)
            L += (sm[i] == -INFINITY) ? 0.f : sl[i] * __expf(sm[i] - M);
        s_M = M;
        Pm[bid] = M;
        Pl[bid] = L;
    }
    __syncthreads();
    // rescale to block max; empty half-wave / empty quarter -> exactly 0
    const float fac = (m_run == -INFINITY) ? 0.f : __expf(m_run - s_M);
    acc.x *= fac; acc.y *= fac; acc.z *= fac; acc.w *= fac;
    // fold upper half-wave onto lower within each 64-lane wave
    acc.x += __shfl_down(acc.x, 32, 64);
    acc.y += __shfl_down(acc.y, 32, 64);
    acc.z += __shfl_down(acc.z, 32, 64);
    acc.w += __shfl_down(acc.w, 32, 64);

    __shared__ float rpart[4][D];         // 2 KB
    const int wave = tid >> 6;            // 0..3
    const int lane64 = tid & 63;
    if (lane64 < 32) ((float4*)rpart[wave])[lane64] = acc;
    __syncthreads();
    if (tid < D) {
        float v = (rpart[0][tid] + rpart[1][tid]) + (rpart[2][tid] + rpart[3][tid]);
        Pacc[(size_t)bid * D + tid] = v;  // unnormalized, scaled to Pm[bid]
    }
}

// ---------------------------------------------------------------------------
// K3 (k_out): final output assembly. out[g] = [h_final | r_final], where
// r_final is combined from the last step's partials (same math as k_cg's C).
// ---------------------------------------------------------------------------
__global__ __launch_bounds__(128) void k_out(const float* __restrict__ g_h,
        const float* __restrict__ Pm, const float* __restrict__ Pl,
        const float* __restrict__ Pacc, float* __restrict__ out) {
    const int g = blockIdx.x;
    const int t = threadIdx.x;            // 0..127
    out[(size_t)g * (2 * D) + t] = g_h[(size_t)g * D + t];
    float m0 = Pm[g * 4 + 0], m1 = Pm[g * 4 + 1];
    float m2 = Pm[g * 4 + 2], m3 = Pm[g * 4 + 3];
    float M = fmaxf(fmaxf(m0, m1), fmaxf(m2, m3));
    float w0 = (m0 == -INFINITY) ? 0.f : __expf(m0 - M);
    float w1 = (m1 == -INFINITY) ? 0.f : __expf(m1 - M);
    float w2 = (m2 == -INFINITY) ? 0.f : __expf(m2 - M);
    float w3 = (m3 == -INFINITY) ? 0.f : __expf(m3 - M);
    float l = w0 * Pl[g * 4 + 0] + w1 * Pl[g * 4 + 1]
            + w2 * Pl[g * 4 + 2] + w3 * Pl[g * 4 + 3];
    float inv = 1.f / (l + 1e-16f);
    float r = (w0 * Pacc[(size_t)(g * 4 + 0) * D + t]
             + w1 * Pacc[(size_t)(g * 4 + 1) * D + t]
             + w2 * Pacc[(size_t)(g * 4 + 2) * D + t]
             + w3 * Pacc[(size_t)(g * 4 + 3) * D + t]) * inv;
    out[(size_t)g * (2 * D) + D + t] = r;
}

// ---------------------------------------------------------------------------
extern "C" void kernel_launch(void* const* d_in, const int* in_sizes, int n_in,
                              void* d_out, int out_size, void* d_ws, size_t ws_size,
                              hipStream_t stream) {
    const float* x    = (const float*)d_in[0];
    const int*   batch= (const int*)d_in[1];
    // d_in[2] = batch_size scalar (fixed at B=512 compile time)
    const float* Wih  = (const float*)d_in[3];
    const float* Whh  = (const float*)d_in[4];
    const float* bih  = (const float*)d_in[5];
    const float* bhh  = (const float*)d_in[6];
    const int n = in_sizes[0] / D;        // 200000

    // workspace layout (4 KB-aligned):
    //   seg    @ 0       (4 KB)
    //   wih_bf @ 4096    (192 KB)
    //   whh_bf @ 200704  (96 KB)
    //   g_h    @ 299008  (256 KB)  [512][128] f32
    //   Pm     @ 561152  (8 KB)    [512*4] f32
    //   Pl     @ 569344  (8 KB)
    //   Pacc   @ 577536  (1 MB)    [512*4][128] f32
    char* ws = (char*)d_ws;
    int* seg              = (int*)(ws);
    unsigned short* wih_bf= (unsigned short*)(ws + 4096);
    unsigned short* whh_bf= (unsigned short*)(ws + 200704);
    float* g_h            = (float*)(ws + 299008);
    float* Pm             = (float*)(ws + 561152);
    float* Pl             = (float*)(ws + 569344);
    float* Pacc           = (float*)(ws + 577536);

    const int total = NW_IH + NW_HH;      // 147456 >= B+1, covers seg too
    k_prep<<<(total + 255) / 256, 256, 0, stream>>>(Wih, Whh, batch, n, wih_bf, whh_bf, seg);

    for (int s = 0; s < STEPS; ++s) {
        k_cg<<<B, 384, 0, stream>>>(wih_bf, whh_bf, bih, bhh, g_h, Pm, Pl, Pacc,
                                    s == 0 ? 1 : 0);
        k_attn_p<<<4 * B, 256, 0, stream>>>(x, g_h, seg, Pm, Pl, Pacc);
    }
    k_out<<<B, 128, 0, stream>>>(g_h, Pm, Pl, Pacc, (float*)d_out);
}

// Round 8
// 266.220 us; speedup vs baseline: 1.0087x; 1.0087x over previous
//
#include <hip/hip_runtime.h>
#include <math.h>

constexpr int D = 128;       // in_channels
constexpr int B = 512;       // batch_size (graphs)
constexpr int STEPS = 3;
constexpr int NW_IH = 3 * D * 2 * D;   // 98304 elems, Wih [3D][2D]
constexpr int NW_HH = 3 * D * D;       // 49152 elems, Whh [3D][D]

__device__ __forceinline__ float sigmoidf_(float x) { return 1.f / (1.f + __expf(-x)); }
// bf16 pair unpack from a uint: low halfword / high halfword -> float (exact)
__device__ __forceinline__ float bflo(unsigned int u) { return __uint_as_float(u << 16); }
__device__ __forceinline__ float bfhi(unsigned int u) { return __uint_as_float(u & 0xffff0000u); }
__device__ __forceinline__ unsigned short f2bf_rn(float f) {
    unsigned int u = __float_as_uint(f);
    u += 0x7fffu + ((u >> 16) & 1u);    // round-to-nearest-even
    return (unsigned short)(u >> 16);
}

// ---------------------------------------------------------------------------
// K0 (prep): weights fp32 -> bf16 row-major, plus segment bounds via binary
// search on sorted batch[].
// ---------------------------------------------------------------------------
__global__ __launch_bounds__(256) void k_prep(const float* __restrict__ Wih,
        const float* __restrict__ Whh, const int* __restrict__ batch, int n,
        unsigned short* __restrict__ wih_bf, unsigned short* __restrict__ whh_bf,
        int* __restrict__ seg) {
    int i = blockIdx.x * blockDim.x + threadIdx.x;
    if (i < NW_IH) wih_bf[i] = f2bf_rn(Wih[i]);
    else if (i < NW_IH + NW_HH) whh_bf[i - NW_IH] = f2bf_rn(Whh[i - NW_IH]);
    if (i <= B) {
        int lo = 0, hi = n;
        while (lo < hi) { int mid = (lo + hi) >> 1; if (batch[mid] < i) lo = mid + 1; else hi = mid; }
        seg[i] = lo;
    }
}

// ---------------------------------------------------------------------------
// K1 (k_cg): combine previous step's attention partials into r, then GRU.
// One block per graph, 384 threads (one gate row each).
// first=1: q_star = 0, h = 0 (step 0) — also initializes g_h (no memset).
// ---------------------------------------------------------------------------
__global__ __launch_bounds__(384) void k_cg(
        const unsigned short* __restrict__ wih_bf,
        const unsigned short* __restrict__ whh_bf,
        const float* __restrict__ bih, const float* __restrict__ bhh,
        float* __restrict__ g_h,
        const float* __restrict__ Pm, const float* __restrict__ Pl,
        const float* __restrict__ Pacc, int first) {
    __shared__ float s_q[2 * D];
    __shared__ float s_h[D];
    __shared__ float s_gi[3 * D], s_gh[3 * D];
    const int g = blockIdx.x;
    const int t = threadIdx.x;

    if (t < D) {
        float hp = first ? 0.f : g_h[(size_t)g * D + t];
        s_h[t] = hp;
        s_q[t] = hp;                      // q part of q_star = previous h
        float r = 0.f;
        if (!first) {
            float m0 = Pm[g * 4 + 0], m1 = Pm[g * 4 + 1];
            float m2 = Pm[g * 4 + 2], m3 = Pm[g * 4 + 3];
            float M = fmaxf(fmaxf(m0, m1), fmaxf(m2, m3));
            float w0 = (m0 == -INFINITY) ? 0.f : __expf(m0 - M);
            float w1 = (m1 == -INFINITY) ? 0.f : __expf(m1 - M);
            float w2 = (m2 == -INFINITY) ? 0.f : __expf(m2 - M);
            float w3 = (m3 == -INFINITY) ? 0.f : __expf(m3 - M);
            float l = w0 * Pl[g * 4 + 0] + w1 * Pl[g * 4 + 1]
                    + w2 * Pl[g * 4 + 2] + w3 * Pl[g * 4 + 3];
            float inv = 1.f / (l + 1e-16f);
            r = (w0 * Pacc[(size_t)(g * 4 + 0) * D + t]
               + w1 * Pacc[(size_t)(g * 4 + 1) * D + t]
               + w2 * Pacc[(size_t)(g * 4 + 2) * D + t]
               + w3 * Pacc[(size_t)(g * 4 + 3) * D + t]) * inv;
        }
        s_q[D + t] = r;                   // r part of q_star
    }
    __syncthreads();

    // ---- gate row t (4 parallel fma chains, bf16x8 per uint4) ----
    {
        float a0 = bih[t], a1 = 0.f, a2 = 0.f, a3 = 0.f;
        const uint4* wr = (const uint4*)(wih_bf + (size_t)t * (2 * D));
#pragma unroll 4
        for (int c = 0; c < (2 * D) / 8; ++c) {     // 32 iters
            uint4 w = wr[c];
            const float* q = &s_q[c * 8];
            a0 = fmaf(bflo(w.x), q[0], a0); a0 = fmaf(bfhi(w.x), q[1], a0);
            a1 = fmaf(bflo(w.y), q[2], a1); a1 = fmaf(bfhi(w.y), q[3], a1);
            a2 = fmaf(bflo(w.z), q[4], a2); a2 = fmaf(bfhi(w.z), q[5], a2);
            a3 = fmaf(bflo(w.w), q[6], a3); a3 = fmaf(bfhi(w.w), q[7], a3);
        }
        s_gi[t] = (a0 + a1) + (a2 + a3);
        float b0 = bhh[t], b1 = 0.f, b2 = 0.f, b3 = 0.f;
        const uint4* vr = (const uint4*)(whh_bf + (size_t)t * D);
#pragma unroll 4
        for (int c = 0; c < D / 8; ++c) {           // 16 iters
            uint4 w = vr[c];
            const float* hh = &s_h[c * 8];
            b0 = fmaf(bflo(w.x), hh[0], b0); b0 = fmaf(bfhi(w.x), hh[1], b0);
            b1 = fmaf(bflo(w.y), hh[2], b1); b1 = fmaf(bfhi(w.y), hh[3], b1);
            b2 = fmaf(bflo(w.z), hh[4], b2); b2 = fmaf(bfhi(w.z), hh[5], b2);
            b3 = fmaf(bflo(w.w), hh[6], b3); b3 = fmaf(bfhi(w.w), hh[7], b3);
        }
        s_gh[t] = (b0 + b1) + (b2 + b3);
    }
    __syncthreads();

    // ---- epilogue: h_new -> g_h ----
    if (t < D) {
        float r  = sigmoidf_(s_gi[t] + s_gh[t]);
        float z  = sigmoidf_(s_gi[D + t] + s_gh[D + t]);
        float nn = tanhf(s_gi[2 * D + t] + r * s_gh[2 * D + t]);
        float hn = (1.f - z) * nn + z * s_h[t];
        g_h[(size_t)g * D + t] = hn;
    }
}

// ---------------------------------------------------------------------------
// K2 (k_attn_p): flash-attention partials, restructured for memory streaming:
//   * 2048 blocks x 256 threads (8 blocks/CU = 32 waves/CU).
//   * Block 4g+j owns quarter j of graph g; WAVE w of the block owns a
//     CONTIGUOUS 1/16 slice of the graph (sequential 1-KB requests ->
//     DRAM row locality; 8192 streams chip-wide).
//   * 2 nodes per wave-iteration (lower/upper 32 lanes), 5-step xor reduce
//     handles both halves in the same instructions.
//   * Explicit 2-deep software pipeline: the load for pair i+2 issues before
//     pair i's reduce chain, overlapping memory latency with the DS/exp chain.
// Writes per-block (Pm, Pl, Pacc[128]) rescaled to the block max.
// ---------------------------------------------------------------------------
__global__ __launch_bounds__(256, 8) void k_attn_p(const float* __restrict__ x,
        const float* __restrict__ g_h, const int* __restrict__ seg,
        float* __restrict__ Pm, float* __restrict__ Pl,
        float* __restrict__ Pacc) {
    const int bid = blockIdx.x;
    const int g = bid >> 2, j = bid & 3;
    const int s = seg[g], e = seg[g + 1];
    const int len = e - s;

    const int tid = threadIdx.x;
    const int wv = tid >> 6;              // wave 0..3
    const int lane = tid & 63;
    const int half = lane >> 5;           // 0 (lower 32 lanes) / 1 (upper)
    const int lane32 = lane & 31;
    const int hw = tid >> 5;              // half-wave id 0..7

    // contiguous slice for this (block, wave): piece j*4+wv of 16
    const int piece = j * 4 + wv;
    const int a = s + (len * piece) / 16;
    const int b = s + (len * (piece + 1)) / 16;
    const int cnt = b - a;

    const float4 qf = ((const float4*)(g_h + (size_t)g * D))[lane32];

    float m_run = -INFINITY, l_run = 0.f;
    float4 acc = {0.f, 0.f, 0.f, 0.f};

    if (cnt > 0) {
        const int iters = (cnt + 1) >> 1;     // node pairs
        // software pipeline, depth 2 (clamped prefetch stays in-bounds)
        int i0 = half;                   // node offset of my half, pair 0
        int i1 = 2 + half;
        float4 xv = ((const float4*)(x + (size_t)(a + (i0 < cnt ? i0 : cnt - 1)) * D))[lane32];
        float4 xn = ((const float4*)(x + (size_t)(a + (i1 < cnt ? i1 : cnt - 1)) * D))[lane32];
        for (int i = 0; i < iters; ++i) {
            int ip = 2 * (i + 2) + half;
            float4 xp = ((const float4*)(x + (size_t)(a + (ip < cnt ? ip : cnt - 1)) * D))[lane32];

            int idx = 2 * i + half;
            float p = fmaf(xv.x, qf.x, fmaf(xv.y, qf.y, fmaf(xv.z, qf.z, xv.w * qf.w)));
            p += __shfl_xor(p, 16, 64);
            p += __shfl_xor(p, 8, 64);
            p += __shfl_xor(p, 4, 64);
            p += __shfl_xor(p, 2, 64);
            p += __shfl_xor(p, 1, 64);
            if (idx >= cnt) p = -INFINITY;     // masked tail (half 1, odd cnt)

            float nm = fmaxf(m_run, p);
            float scale = (m_run == -INFINITY) ? 0.f : __expf(m_run - nm);
            float aw    = (p     == -INFINITY) ? 0.f : __expf(p - nm);
            l_run = fmaf(l_run, scale, aw);
            acc.x = fmaf(acc.x, scale, aw * xv.x);
            acc.y = fmaf(acc.y, scale, aw * xv.y);
            acc.z = fmaf(acc.z, scale, aw * xv.z);
            acc.w = fmaf(acc.w, scale, aw * xv.w);
            m_run = nm;

            xv = xn; xn = xp;
        }
    }

    __shared__ float sm[8], sl[8];
    __shared__ float s_M;
    if (lane32 == 0) { sm[hw] = m_run; sl[hw] = l_run; }
    __syncthreads();
    if (tid == 0) {
        float M = -INFINITY;
#pragma unroll
        for (int i = 0; i < 8; ++i) M = fmaxf(M, sm[i]);
        float L = 0.f;
#pragma unroll
        for (int i = 0; i < 8; ++i)
            L += (sm[i] == -INFINITY) ? 0.f : sl[i] * __expf(sm[i] - M);
        s_M = M;
        Pm[bid] = M;
        Pl[bid] = L;
    }
    __syncthreads();
    // rescale each half-wave's acc to block max; empty -> exactly 0
    const float fac = (m_run == -INFINITY) ? 0.f : __expf(m_run - s_M);
    acc.x *= fac; acc.y *= fac; acc.z *= fac; acc.w *= fac;
    // fold upper half-wave onto lower within each 64-lane wave
    acc.x += __shfl_down(acc.x, 32, 64);
    acc.y += __shfl_down(acc.y, 32, 64);
    acc.z += __shfl_down(acc.z, 32, 64);
    acc.w += __shfl_down(acc.w, 32, 64);

    __shared__ float rpart[4][D];         // 2 KB
    const int lane64 = tid & 63;
    if (lane64 < 32) ((float4*)rpart[wv])[lane64] = acc;
    __syncthreads();
    if (tid < D) {
        float v = (rpart[0][tid] + rpart[1][tid]) + (rpart[2][tid] + rpart[3][tid]);
        Pacc[(size_t)bid * D + tid] = v;  // unnormalized, scaled to Pm[bid]
    }
}

// ---------------------------------------------------------------------------
// K3 (k_out): final output assembly. out[g] = [h_final | r_final].
// ---------------------------------------------------------------------------
__global__ __launch_bounds__(128) void k_out(const float* __restrict__ g_h,
        const float* __restrict__ Pm, const float* __restrict__ Pl,
        const float* __restrict__ Pacc, float* __restrict__ out) {
    const int g = blockIdx.x;
    const int t = threadIdx.x;            // 0..127
    out[(size_t)g * (2 * D) + t] = g_h[(size_t)g * D + t];
    float m0 = Pm[g * 4 + 0], m1 = Pm[g * 4 + 1];
    float m2 = Pm[g * 4 + 2], m3 = Pm[g * 4 + 3];
    float M = fmaxf(fmaxf(m0, m1), fmaxf(m2, m3));
    float w0 = (m0 == -INFINITY) ? 0.f : __expf(m0 - M);
    float w1 = (m1 == -INFINITY) ? 0.f : __expf(m1 - M);
    float w2 = (m2 == -INFINITY) ? 0.f : __expf(m2 - M);
    float w3 = (m3 == -INFINITY) ? 0.f : __expf(m3 - M);
    float l = w0 * Pl[g * 4 + 0] + w1 * Pl[g * 4 + 1]
            + w2 * Pl[g * 4 + 2] + w3 * Pl[g * 4 + 3];
    float inv = 1.f / (l + 1e-16f);
    float r = (w0 * Pacc[(size_t)(g * 4 + 0) * D + t]
             + w1 * Pacc[(size_t)(g * 4 + 1) * D + t]
             + w2 * Pacc[(size_t)(g * 4 + 2) * D + t]
             + w3 * Pacc[(size_t)(g * 4 + 3) * D + t]) * inv;
    out[(size_t)g * (2 * D) + D + t] = r;
}

// ---------------------------------------------------------------------------
extern "C" void kernel_launch(void* const* d_in, const int* in_sizes, int n_in,
                              void* d_out, int out_size, void* d_ws, size_t ws_size,
                              hipStream_t stream) {
    const float* x    = (const float*)d_in[0];
    const int*   batch= (const int*)d_in[1];
    // d_in[2] = batch_size scalar (fixed at B=512 compile time)
    const float* Wih  = (const float*)d_in[3];
    const float* Whh  = (const float*)d_in[4];
    const float* bih  = (const float*)d_in[5];
    const float* bhh  = (const float*)d_in[6];
    const int n = in_sizes[0] / D;        // 200000

    // workspace layout (4 KB-aligned):
    //   seg    @ 0       (4 KB)
    //   wih_bf @ 4096    (192 KB)
    //   whh_bf @ 200704  (96 KB)
    //   g_h    @ 299008  (256 KB)  [512][128] f32
    //   Pm     @ 561152  (8 KB)    [512*4] f32
    //   Pl     @ 569344  (8 KB)
    //   Pacc   @ 577536  (1 MB)    [512*4][128] f32
    char* ws = (char*)d_ws;
    int* seg              = (int*)(ws);
    unsigned short* wih_bf= (unsigned short*)(ws + 4096);
    unsigned short* whh_bf= (unsigned short*)(ws + 200704);
    float* g_h            = (float*)(ws + 299008);
    float* Pm             = (float*)(ws + 561152);
    float* Pl             = (float*)(ws + 569344);
    float* Pacc           = (float*)(ws + 577536);

    const int total = NW_IH + NW_HH;      // 147456 >= B+1, covers seg too
    k_prep<<<(total + 255) / 256, 256, 0, stream>>>(Wih, Whh, batch, n, wih_bf, whh_bf, seg);

    for (int s = 0; s < STEPS; ++s) {
        k_cg<<<B, 384, 0, stream>>>(wih_bf, whh_bf, bih, bhh, g_h, Pm, Pl, Pacc,
                                    s == 0 ? 1 : 0);
        k_attn_p<<<4 * B, 256, 0, stream>>>(x, g_h, seg, Pm, Pl, Pacc);
    }
    k_out<<<B, 128, 0, stream>>>(g_h, Pm, Pl, Pacc, (float*)d_out);
}

// Round 9
// 253.346 us; speedup vs baseline: 1.0600x; 1.0508x over previous
//
#include <hip/hip_runtime.h>
#include <math.h>

constexpr int D = 128;       // in_channels
constexpr int B = 512;       // batch_size (graphs)
constexpr int STEPS = 3;
constexpr int NW_IH = 3 * D * 2 * D;   // 98304 elems, Wih [3D][2D]
constexpr int NW_HH = 3 * D * D;       // 49152 elems, Whh [3D][D]

__device__ __forceinline__ float sigmoidf_(float x) { return 1.f / (1.f + __expf(-x)); }
// bf16 pair unpack from a uint: low halfword / high halfword -> float (exact)
__device__ __forceinline__ float bflo(unsigned int u) { return __uint_as_float(u << 16); }
__device__ __forceinline__ float bfhi(unsigned int u) { return __uint_as_float(u & 0xffff0000u); }
__device__ __forceinline__ unsigned short f2bf_rn(float f) {
    unsigned int u = __float_as_uint(f);
    u += 0x7fffu + ((u >> 16) & 1u);    // round-to-nearest-even
    return (unsigned short)(u >> 16);
}

// ---------------------------------------------------------------------------
// K0 (prep): weights fp32 -> bf16 row-major, plus segment bounds via binary
// search on sorted batch[] (seg[g] = first index with batch[i] >= g).
// ---------------------------------------------------------------------------
__global__ __launch_bounds__(256) void k_prep(const float* __restrict__ Wih,
        const float* __restrict__ Whh, const int* __restrict__ batch, int n,
        unsigned short* __restrict__ wih_bf, unsigned short* __restrict__ whh_bf,
        int* __restrict__ seg) {
    int i = blockIdx.x * blockDim.x + threadIdx.x;
    if (i < NW_IH) wih_bf[i] = f2bf_rn(Wih[i]);
    else if (i < NW_IH + NW_HH) whh_bf[i - NW_IH] = f2bf_rn(Whh[i - NW_IH]);
    if (i <= B) {
        int lo = 0, hi = n;
        while (lo < hi) { int mid = (lo + hi) >> 1; if (batch[mid] < i) lo = mid + 1; else hi = mid; }
        seg[i] = lo;
    }
}

// ---------------------------------------------------------------------------
// K1 (fused Set2Set): one block per graph, *512* threads (8 waves), all 3
// steps inside. 4 blocks/CU x 8 waves = 32 waves/CU: same total occupancy as
// the 1024-thread version, but 4 INDEPENDENT blocks per CU — when one block
// sits in its GRU/combine barrier phases, three others keep streaming x.
// GRU phase also uses 384/512 threads (75% vs 37.5% before).
//   GRU:  threads 0..383 compute gate rows (bf16 weights row-major, uint4
//         loads, 4 parallel fma chains).
//   Attn: flash-style single pass; 16 half-waves, 1 node per half-wave per
//         iter (float4/lane dot + 5-step xor reduce, online m/l/acc).
//   Combine: 16 (m,l) pairs via 4-step butterfly on wave 0.
// __launch_bounds__(512,8): VGPR<=64 -> 4 blocks/CU.
// ---------------------------------------------------------------------------
__global__ __launch_bounds__(512, 8) void k_set2set(
        const float* __restrict__ x,
        const unsigned short* __restrict__ wih_bf,
        const unsigned short* __restrict__ whh_bf,
        const float* __restrict__ bih, const float* __restrict__ bhh,
        const int* __restrict__ seg, float* __restrict__ out) {
    __shared__ float s_q[2 * D];          // q_star for this graph: [q | r]
    __shared__ float s_h[D];
    __shared__ float s_gi[3 * D], s_gh[3 * D];
    __shared__ float sm[16], sl[16];
    __shared__ float s_M, s_inv;
    __shared__ float rpart[8][D];         // 4 KB

    const int b = blockIdx.x;
    const int tid = threadIdx.x;
    const int start = seg[b], end = seg[b + 1];
    const int lane32 = tid & 31;
    const int hw = tid >> 5;              // half-wave id 0..15

    if (tid < 2 * D) s_q[tid] = 0.f;
    if (tid < D) s_h[tid] = 0.f;
    __syncthreads();

    for (int step = 0; step < STEPS; ++step) {
        // ---- GRU gate rows (384 of 512 threads, 4 parallel fma chains) ----
        if (tid < 3 * D) {
            const int t = tid;
            float a0 = bih[t], a1 = 0.f, a2 = 0.f, a3 = 0.f;
            const uint4* wr = (const uint4*)(wih_bf + (size_t)t * (2 * D));
#pragma unroll 4
            for (int c = 0; c < (2 * D) / 8; ++c) {     // 32 iters
                uint4 w = wr[c];
                const float* q = &s_q[c * 8];
                a0 = fmaf(bflo(w.x), q[0], a0); a0 = fmaf(bfhi(w.x), q[1], a0);
                a1 = fmaf(bflo(w.y), q[2], a1); a1 = fmaf(bfhi(w.y), q[3], a1);
                a2 = fmaf(bflo(w.z), q[4], a2); a2 = fmaf(bfhi(w.z), q[5], a2);
                a3 = fmaf(bflo(w.w), q[6], a3); a3 = fmaf(bfhi(w.w), q[7], a3);
            }
            s_gi[t] = (a0 + a1) + (a2 + a3);
            float b0 = bhh[t], b1 = 0.f, b2 = 0.f, b3 = 0.f;
            const uint4* vr = (const uint4*)(whh_bf + (size_t)t * D);
#pragma unroll 4
            for (int c = 0; c < D / 8; ++c) {           // 16 iters
                uint4 w = vr[c];
                const float* hh = &s_h[c * 8];
                b0 = fmaf(bflo(w.x), hh[0], b0); b0 = fmaf(bfhi(w.x), hh[1], b0);
                b1 = fmaf(bflo(w.y), hh[2], b1); b1 = fmaf(bfhi(w.y), hh[3], b1);
                b2 = fmaf(bflo(w.z), hh[4], b2); b2 = fmaf(bfhi(w.z), hh[5], b2);
                b3 = fmaf(bflo(w.w), hh[6], b3); b3 = fmaf(bfhi(w.w), hh[7], b3);
            }
            s_gh[t] = (b0 + b1) + (b2 + b3);
        }
        __syncthreads();
        // ---- GRU epilogue ----
        if (tid < D) {
            const int t = tid;
            float r  = sigmoidf_(s_gi[t] + s_gh[t]);
            float z  = sigmoidf_(s_gi[D + t] + s_gh[D + t]);
            float nn = tanhf(s_gi[2 * D + t] + r * s_gh[2 * D + t]);
            float hn = (1.f - z) * nn + z * s_h[t];
            s_h[t] = hn;
            s_q[t] = hn;                  // q part of q_star
        }
        __syncthreads();

        // ---- flash attention: 1 node/half-wave/iter, stride 16 ----
        const float4 qf = *(const float4*)&s_h[lane32 * 4];
        float m_run = -INFINITY, l_run = 0.f;
        float4 acc = {0.f, 0.f, 0.f, 0.f};
        for (int node = start + hw; node < end; node += 16) {
            float4 xv = ((const float4*)(x + (size_t)node * D))[lane32];
            float p = fmaf(xv.x, qf.x, fmaf(xv.y, qf.y, fmaf(xv.z, qf.z, xv.w * qf.w)));
            p += __shfl_xor(p, 16, 64);
            p += __shfl_xor(p, 8, 64);
            p += __shfl_xor(p, 4, 64);
            p += __shfl_xor(p, 2, 64);
            p += __shfl_xor(p, 1, 64);
            float nm = fmaxf(m_run, p);
            float scale = __expf(m_run - nm);   // 0 on first iter
            float a = __expf(p - nm);
            l_run = fmaf(l_run, scale, a);
            acc.x = fmaf(acc.x, scale, a * xv.x);
            acc.y = fmaf(acc.y, scale, a * xv.y);
            acc.z = fmaf(acc.z, scale, a * xv.z);
            acc.w = fmaf(acc.w, scale, a * xv.w);
            m_run = nm;
        }
        if (lane32 == 0) { sm[hw] = m_run; sl[hw] = l_run; }
        __syncthreads();
        // ---- butterfly combine of 16 (m,l) pairs on wave 0 ----
        if (tid < 64) {
            float m = sm[tid & 15], l = sl[tid & 15];
#pragma unroll
            for (int s = 8; s >= 1; s >>= 1) {
                float mo = __shfl_xor(m, s, 64);
                float lo = __shfl_xor(l, s, 64);
                float nm2 = fmaxf(m, mo);
                float t1 = (m  == -INFINITY) ? 0.f : l  * __expf(m  - nm2);
                float t2 = (mo == -INFINITY) ? 0.f : lo * __expf(mo - nm2);
                l = t1 + t2; m = nm2;
            }
            if (tid == 0) { s_M = m; s_inv = 1.f / (l + 1e-16f); }
        }
        __syncthreads();
        // rescale to global max; empty half-wave / empty graph -> exactly 0
        const float fac = (m_run == -INFINITY) ? 0.f : __expf(m_run - s_M);
        acc.x *= fac; acc.y *= fac; acc.z *= fac; acc.w *= fac;
        // fold upper half-wave onto lower within each 64-lane wave
        acc.x += __shfl_down(acc.x, 32, 64);
        acc.y += __shfl_down(acc.y, 32, 64);
        acc.z += __shfl_down(acc.z, 32, 64);
        acc.w += __shfl_down(acc.w, 32, 64);
        const int wave = tid >> 6;        // 0..7
        const int lane64 = tid & 63;
        if (lane64 < 32) ((float4*)rpart[wave])[lane64] = acc;
        __syncthreads();
        if (tid < D) {
            float v = 0.f;
#pragma unroll
            for (int w = 0; w < 8; ++w) v += rpart[w][tid];
            s_q[D + tid] = v * s_inv;     // r part of q_star
        }
        __syncthreads();                  // s_q complete for next GRU / output
    }

    // ---- write q_star row (s_q is exactly [q | r]) ----
    if (tid < 2 * D) out[(size_t)b * (2 * D) + tid] = s_q[tid];
}

// ---------------------------------------------------------------------------
extern "C" void kernel_launch(void* const* d_in, const int* in_sizes, int n_in,
                              void* d_out, int out_size, void* d_ws, size_t ws_size,
                              hipStream_t stream) {
    const float* x    = (const float*)d_in[0];
    const int*   batch= (const int*)d_in[1];
    // d_in[2] = batch_size scalar (fixed at B=512 compile time)
    const float* Wih  = (const float*)d_in[3];
    const float* Whh  = (const float*)d_in[4];
    const float* bih  = (const float*)d_in[5];
    const float* bhh  = (const float*)d_in[6];
    const int n = in_sizes[0] / D;        // 200000

    // workspace: seg (4 KB pad) | wih_bf (192 KB) | whh_bf (96 KB)
    char* ws = (char*)d_ws;
    int* seg = (int*)ws;
    unsigned short* wih_bf = (unsigned short*)(ws + 4096);
    unsigned short* whh_bf = (unsigned short*)(ws + 4096 + (size_t)NW_IH * 2);

    const int total = NW_IH + NW_HH;      // 147456 >= B+1, covers seg too
    k_prep<<<(total + 255) / 256, 256, 0, stream>>>(Wih, Whh, batch, n, wih_bf, whh_bf, seg);
    k_set2set<<<B, 512, 0, stream>>>(x, wih_bf, whh_bf, bih, bhh, seg, (float*)d_out);
}